// Round 2
// baseline (1227.614 us; speedup 1.0000x reference)
//
#include <hip/hip_runtime.h>
#include <hip/hip_bf16.h>

// Problem constants
#define BATCH   16384
#define NIN     784
#define DIM     64
#define BANKS   6
#define NH      384      // BANKS*DIM
#define NLAYERS 6
#define NOUT    10
#define EPS_BN  1e-5f

// ---------------------------------------------------------------------------
// Stage 1: column stats (two-stage, deterministic).  src [B, C] row-major.
// grid (ceil(C/256), 64), block 256.  Each block handles 256 rows x 256 cols.
__global__ __launch_bounds__(256) void stats_partial(
        const float* __restrict__ src, int C, int applyRelu,
        float* __restrict__ psum, float* __restrict__ psq) {
    int c = blockIdx.x * 256 + threadIdx.x;
    if (c >= C) return;
    int r0 = blockIdx.y * 256;
    float s = 0.f, q = 0.f;
    for (int r = r0; r < r0 + 256; ++r) {
        float v = src[(size_t)r * C + c];
        if (applyRelu) v = fmaxf(v, 0.f);
        s += v; q += v * v;
    }
    psum[blockIdx.y * 1024 + c] = s;
    psq [blockIdx.y * 1024 + c] = q;
}

// Reduce 64 partials; produce per-feature affine fold: y = a*relu(x) + c
__global__ __launch_bounds__(256) void stats_finalize(
        const float* __restrict__ psum, const float* __restrict__ psq, int C,
        const float* __restrict__ gamma, const float* __restrict__ beta,
        float* __restrict__ a_out, float* __restrict__ c_out) {
    int c = blockIdx.x * 256 + threadIdx.x;
    if (c >= C) return;
    float s = 0.f, q = 0.f;
    for (int i = 0; i < 64; ++i) { s += psum[i * 1024 + c]; q += psq[i * 1024 + c]; }
    const float invB = 1.f / (float)BATCH;
    float mu  = s * invB;
    float var = q * invB - mu * mu;
    float rs  = rsqrtf(var + EPS_BN);
    float g   = gamma[c];
    a_out[c] = g * rs;
    c_out[c] = beta[c] - g * mu * rs;
}

// W'[j,n] = a[n] * W_in[j,n]   (j = k*64+d, 384x784)
__global__ __launch_bounds__(256) void scale_win(
        const float* __restrict__ W_in, const float* __restrict__ a,
        float* __restrict__ Wp) {
    int idx = blockIdx.x * 256 + threadIdx.x;
    if (idx >= NH * NIN) return;
    int n = idx % NIN;
    Wp[idx] = W_in[idx] * a[n];
}

// b'[j] = b_in[j] + sum_n c[n]*W_in[j,n].  grid 384, block 64 (one wave).
__global__ __launch_bounds__(64) void bias_in(
        const float* __restrict__ W_in, const float* __restrict__ b_in,
        const float* __restrict__ cvec, float* __restrict__ bp) {
    int j = blockIdx.x;
    int lane = threadIdx.x;
    float s = 0.f;
    for (int n = lane; n < NIN; n += 64) s += cvec[n] * W_in[j * NIN + n];
    for (int m = 1; m < 64; m <<= 1) s += __shfl_xor(s, m, 64);
    if (lane == 0) bp[j] = b_in[j] + s;
}

// ---------------------------------------------------------------------------
// Input GEMM: pre[b,j] = sum_n X[b,n]*Wp[j,n] + bp[j].
// M=16384, N=384, K=784. Tile 64x64, BK=32, 4x4 micro.
#define BK 32
__global__ __launch_bounds__(256) void gemm_in(
        const float* __restrict__ X, const float* __restrict__ Wp,
        const float* __restrict__ bp, float* __restrict__ out) {
    __shared__ float As[64][BK + 1];
    __shared__ float Bs[64][BK + 1];
    int tid = threadIdx.x;
    int tx = tid & 15, ty = tid >> 4;
    int m0 = blockIdx.x * 64;
    int n0 = blockIdx.y * 64;
    float acc[4][4] = {};
    for (int k0 = 0; k0 < NIN; k0 += BK) {
        for (int i = 0; i < 8; ++i) {
            int e = tid + i * 256;
            int m = e >> 5, k = e & 31;
            int kk = k0 + k;
            As[m][k] = (kk < NIN) ? X[(size_t)(m0 + m) * NIN + kk] : 0.f;
        }
        for (int i = 0; i < 8; ++i) {
            int e = tid + i * 256;
            int n = e >> 5, k = e & 31;
            int kk = k0 + k;
            Bs[n][k] = (kk < NIN) ? Wp[(size_t)(n0 + n) * NIN + kk] : 0.f;
        }
        __syncthreads();
        for (int kk = 0; kk < BK; ++kk) {
            float a[4], b[4];
            #pragma unroll
            for (int i = 0; i < 4; ++i) a[i] = As[ty * 4 + i][kk];
            #pragma unroll
            for (int j = 0; j < 4; ++j) b[j] = Bs[tx * 4 + j][kk];
            #pragma unroll
            for (int i = 0; i < 4; ++i)
                #pragma unroll
                for (int j = 0; j < 4; ++j) acc[i][j] += a[i] * b[j];
        }
        __syncthreads();
    }
    for (int i = 0; i < 4; ++i) {
        int m = m0 + ty * 4 + i;
        for (int j = 0; j < 4; ++j) {
            int n = n0 + tx * 4 + j;
            out[(size_t)m * NH + n] = acc[i][j] + bp[n];
        }
    }
}

// ---------------------------------------------------------------------------
// Normalize: actsN[b,j] = a[j]*relu(pre[b,j]) + c[j]   (vectorized float4)
__global__ __launch_bounds__(256) void norm_kernel(
        const float* __restrict__ pre, const float* __restrict__ a,
        const float* __restrict__ c, float* __restrict__ actsN) {
    int idx = blockIdx.x * 256 + threadIdx.x;   // over B*NH/4
    float4 v = ((const float4*)pre)[idx];
    int j = (idx % (NH / 4)) * 4;
    float4 r;
    r.x = a[j + 0] * fmaxf(v.x, 0.f) + c[j + 0];
    r.y = a[j + 1] * fmaxf(v.y, 0.f) + c[j + 1];
    r.z = a[j + 2] * fmaxf(v.z, 0.f) + c[j + 2];
    r.w = a[j + 3] * fmaxf(v.w, 0.f) + c[j + 3];
    ((float4*)actsN)[idx] = r;
}

// ---------------------------------------------------------------------------
// Gates: gate[b,s,t] = clip(dot64(actsN[b,s,:], Wg_l[s,t,:]),0,1); tg accumulate.
// grid B/4, block 256 (4 waves, wave per row).
__global__ __launch_bounds__(256) void gate_kernel(
        const float* __restrict__ actsN, const float* __restrict__ Wg_l,
        float* __restrict__ gate, float* __restrict__ tg, int firstLayer) {
    int lane = threadIdx.x & 63;
    int w = threadIdx.x >> 6;
    int b = blockIdx.x * 4 + w;
    float a[BANKS];
    #pragma unroll
    for (int s = 0; s < BANKS; ++s) a[s] = actsN[(size_t)b * NH + s * 64 + lane];
    float gsum = 0.f, gval = 0.f;
    #pragma unroll
    for (int s = 0; s < BANKS; ++s) {
        #pragma unroll
        for (int t = 0; t < BANKS; ++t) {
            float p = a[s] * Wg_l[(s * 6 + t) * 64 + lane];
            for (int m = 1; m < 64; m <<= 1) p += __shfl_xor(p, m, 64);
            float g = fminf(fmaxf(p, 0.f), 1.f);
            gsum += g;
            if (lane == s * 6 + t) gval = g;
        }
    }
    if (lane < 36) gate[(size_t)b * 36 + lane] = gval;
    if (lane == 0) tg[b] = (firstLayer ? 0.f : tg[b]) + gsum;
}

// ---------------------------------------------------------------------------
// Layer data GEMM for one target bank t = blockIdx.y:
// pre[b,t,e] = sum_{s,d} gate[b,s,t]*actsN[b,s,d]*Wd_l[s,t,e,d]
//            + sum_s gate[b,s,t]*bd_l[s,t,e]
__global__ __launch_bounds__(256) void layer_data(
        const float* __restrict__ actsN, const float* __restrict__ gate,
        const float* __restrict__ Wd_l, const float* __restrict__ bd_l,
        float* __restrict__ pre) {
    __shared__ float As[64][BK + 1];
    __shared__ float Bs[64][BK + 1];
    __shared__ float gs[64][BANKS];
    int tid = threadIdx.x;
    int t = blockIdx.y;
    int m0 = blockIdx.x * 64;
    // FIX: 384 entries, 256 threads -> strided loop (was `if (tid<384)`, leaving
    // gs[43..63][*] uninitialized -> NaN)
    for (int e = tid; e < 64 * BANKS; e += 256) {
        int m = e / BANKS, s = e % BANKS;
        gs[m][s] = gate[(size_t)(m0 + m) * 36 + s * 6 + t];
    }
    __syncthreads();
    int tx = tid & 15, ty = tid >> 4;
    float acc[4][4] = {};
    for (int k0 = 0; k0 < NH; k0 += BK) {
        int s = k0 >> 6;          // which source bank this K-tile lives in
        int d0 = k0 & 63;
        for (int i = 0; i < 8; ++i) {
            int e = tid + i * 256;
            int m = e >> 5, k = e & 31;
            As[m][k] = actsN[(size_t)(m0 + m) * NH + k0 + k] * gs[m][s];
        }
        const float* wbase = Wd_l + ((s * 6 + t) * 64) * 64 + d0;  // + e*64 + k
        for (int i = 0; i < 8; ++i) {
            int e2 = tid + i * 256;
            int n = e2 >> 5, k = e2 & 31;
            Bs[n][k] = wbase[n * 64 + k];
        }
        __syncthreads();
        for (int kk = 0; kk < BK; ++kk) {
            float a[4], b[4];
            #pragma unroll
            for (int i = 0; i < 4; ++i) a[i] = As[ty * 4 + i][kk];
            #pragma unroll
            for (int j = 0; j < 4; ++j) b[j] = Bs[tx * 4 + j][kk];
            #pragma unroll
            for (int i = 0; i < 4; ++i)
                #pragma unroll
                for (int j = 0; j < 4; ++j) acc[i][j] += a[i] * b[j];
        }
        __syncthreads();
    }
    for (int i = 0; i < 4; ++i) {
        int m = ty * 4 + i;
        for (int j = 0; j < 4; ++j) {
            int e = tx * 4 + j;
            float bias = 0.f;
            #pragma unroll
            for (int s = 0; s < BANKS; ++s) bias += gs[m][s] * bd_l[(s * 6 + t) * 64 + e];
            pre[(size_t)(m0 + m) * NH + t * 64 + e] = acc[i][j] + bias;
        }
    }
}

// ---------------------------------------------------------------------------
// Output head: out[b,o] = sum_{s,d} actsN[b,s*64+d]*W_out[s,o,d]; also copy tg.
__global__ __launch_bounds__(256) void out_kernel(
        const float* __restrict__ actsN, const float* __restrict__ W_out,
        const float* __restrict__ tg, float* __restrict__ dout) {
    int lane = threadIdx.x & 63;
    int w = threadIdx.x >> 6;
    int b = blockIdx.x * 4 + w;
    float a[BANKS];
    #pragma unroll
    for (int s = 0; s < BANKS; ++s) a[s] = actsN[(size_t)b * NH + s * 64 + lane];
    float ov = 0.f;
    #pragma unroll
    for (int o = 0; o < NOUT; ++o) {
        float p = 0.f;
        #pragma unroll
        for (int s = 0; s < BANKS; ++s) p += a[s] * W_out[(s * NOUT + o) * 64 + lane];
        for (int m = 1; m < 64; m <<= 1) p += __shfl_xor(p, m, 64);
        if (lane == o) ov = p;
    }
    if (lane < NOUT) dout[(size_t)b * NOUT + lane] = ov;
    if (lane == 0) dout[(size_t)BATCH * NOUT + b] = tg[b];
}

// ---------------------------------------------------------------------------
extern "C" void kernel_launch(void* const* d_in, const int* in_sizes, int n_in,
                              void* d_out, int out_size, void* d_ws, size_t ws_size,
                              hipStream_t stream) {
    const float* x        = (const float*)d_in[0];
    const float* gamma_in = (const float*)d_in[1];
    const float* beta_in  = (const float*)d_in[2];
    const float* W_in     = (const float*)d_in[3];
    const float* b_in     = (const float*)d_in[4];
    const float* Wg       = (const float*)d_in[5];
    const float* Wd       = (const float*)d_in[6];
    const float* bd       = (const float*)d_in[7];
    const float* gamma_h  = (const float*)d_in[8];
    const float* beta_h   = (const float*)d_in[9];
    const float* W_out    = (const float*)d_in[10];
    float* dout = (float*)d_out;
    float* ws = (float*)d_ws;

    // workspace layout (float offsets)
    float* psum  = ws;                 // 64*1024
    float* psq   = ws + 65536;         // 64*1024
    float* avec  = ws + 131072;        // 1024
    float* cvec  = ws + 132096;        // 1024
    float* Wp    = ws + 133120;        // 384*784 = 301056
    float* bp    = ws + 434176;        // 1024
    float* pre   = ws + 435200;        // B*384
    float* actsN = ws + 6726656;       // B*384
    float* gateb = ws + 13018112;      // B*36
    float* tg    = ws + 13607936;      // B

    dim3 blk(256);

    // ---- input BN folded into GEMM weights
    stats_partial<<<dim3(4, 64), blk, 0, stream>>>(x, NIN, 0, psum, psq);
    stats_finalize<<<dim3(4), blk, 0, stream>>>(psum, psq, NIN, gamma_in, beta_in, avec, cvec);
    scale_win<<<dim3((NH * NIN + 255) / 256), blk, 0, stream>>>(W_in, avec, Wp);
    bias_in<<<dim3(NH), dim3(64), 0, stream>>>(W_in, b_in, cvec, bp);

    // ---- input GEMM -> pre (raw, relu applied downstream)
    gemm_in<<<dim3(BATCH / 64, NH / 64), blk, 0, stream>>>(x, Wp, bp, pre);

    // ---- hidden layers
    for (int j = 0; j < NLAYERS; ++j) {
        stats_partial<<<dim3(2, 64), blk, 0, stream>>>(pre, NH, 1, psum, psq);
        stats_finalize<<<dim3(2), blk, 0, stream>>>(psum, psq, NH,
                gamma_h + j * NH, beta_h + j * NH, avec, cvec);
        norm_kernel<<<dim3(BATCH * NH / 4 / 256), blk, 0, stream>>>(pre, avec, cvec, actsN);
        if (j < NLAYERS - 1) {
            int l = j;
            gate_kernel<<<dim3(BATCH / 4), blk, 0, stream>>>(
                    actsN, Wg + (size_t)l * 36 * 64, gateb, tg, l == 0);
            layer_data<<<dim3(BATCH / 64, BANKS), blk, 0, stream>>>(
                    actsN, gateb, Wd + (size_t)l * 36 * 4096, bd + (size_t)l * 36 * 64, pre);
        }
    }

    // ---- output head + total_gate copy
    out_kernel<<<dim3(BATCH / 4), blk, 0, stream>>>(actsN, W_out, tg, dout);
}

// Round 4
// 966.197 us; speedup vs baseline: 1.2706x; 1.2706x over previous
//
#include <hip/hip_runtime.h>
#include <hip/hip_bf16.h>

#define BATCH   16384
#define NIN     784
#define NH      384
#define NLAYERS 6
#define NOUT    10
#define EPS_BN  1e-5f
#define LOSCALE 2048.0f
#define LOINV   (1.0f/2048.0f)
#define NPART   32
#define PSTRIDE 1024

typedef __attribute__((ext_vector_type(8))) _Float16 f16x8;
typedef __attribute__((ext_vector_type(4))) _Float16 f16x4;
typedef __attribute__((ext_vector_type(4))) float f32x4;

// ---------------------------------------------------------------------------
// Column stats (two-stage, deterministic).  src [B, C] f32 row-major.
__global__ __launch_bounds__(256) void stats_partial(
        const float* __restrict__ src, int C, int applyRelu,
        float* __restrict__ psum, float* __restrict__ psq) {
    int c = blockIdx.x * 256 + threadIdx.x;
    if (c >= C) return;
    int r0 = blockIdx.y * (BATCH / NPART);
    float s = 0.f, q = 0.f;
    for (int r = r0; r < r0 + BATCH / NPART; ++r) {
        float v = src[(size_t)r * C + c];
        if (applyRelu) v = fmaxf(v, 0.f);
        s += v; q += v * v;
    }
    psum[blockIdx.y * PSTRIDE + c] = s;
    psq [blockIdx.y * PSTRIDE + c] = q;
}

__global__ __launch_bounds__(256) void stats_finalize(
        const float* __restrict__ psum, const float* __restrict__ psq, int C,
        const float* __restrict__ gamma, const float* __restrict__ beta,
        float* __restrict__ a_out, float* __restrict__ c_out) {
    int c = blockIdx.x * 256 + threadIdx.x;
    if (c >= C) return;
    float s = 0.f, q = 0.f;
    for (int i = 0; i < NPART; ++i) { s += psum[i * PSTRIDE + c]; q += psq[i * PSTRIDE + c]; }
    const float invB = 1.f / (float)BATCH;
    float mu  = s * invB;
    float var = q * invB - mu * mu;
    float rs  = rsqrtf(var + EPS_BN);
    float g   = gamma[c];
    a_out[c] = g * rs;
    c_out[c] = beta[c] - g * mu * rs;
}

// ---------------------------------------------------------------------------
// Wp[j][n] = a[n]*W_in[j][n] split into f16 hi/lo(scaled).  4 elems/thread.
__global__ __launch_bounds__(256) void scale_win_hl(
        const float* __restrict__ W_in, const float* __restrict__ a,
        _Float16* __restrict__ whi, _Float16* __restrict__ wlo) {
    int i = blockIdx.x * 256 + threadIdx.x;
    if (i >= NH * NIN / 4) return;
    int n = (i * 4) % NIN;
    float4 wv = ((const float4*)W_in)[i];
    float v[4] = { wv.x * a[n], wv.y * a[n + 1], wv.z * a[n + 2], wv.w * a[n + 3] };
    f16x4 h4, l4;
    #pragma unroll
    for (int j = 0; j < 4; ++j) {
        _Float16 h = (_Float16)v[j];
        h4[j] = h;
        l4[j] = (_Float16)((v[j] - (float)h) * LOSCALE);
    }
    *(f16x4*)(whi + (size_t)i * 4) = h4;
    *(f16x4*)(wlo + (size_t)i * 4) = l4;
}

// f32 -> f16 hi/lo(scaled) split, 4 elems/thread (for Wd chunks)
__global__ __launch_bounds__(256) void conv_hl(
        const float* __restrict__ src, _Float16* __restrict__ hi,
        _Float16* __restrict__ lo, int n4) {
    int i = blockIdx.x * 256 + threadIdx.x;
    if (i >= n4) return;
    float4 wv = ((const float4*)src)[i];
    float v[4] = { wv.x, wv.y, wv.z, wv.w };
    f16x4 h4, l4;
    #pragma unroll
    for (int j = 0; j < 4; ++j) {
        _Float16 h = (_Float16)v[j];
        h4[j] = h;
        l4[j] = (_Float16)((v[j] - (float)h) * LOSCALE);
    }
    *(f16x4*)(hi + (size_t)i * 4) = h4;
    *(f16x4*)(lo + (size_t)i * 4) = l4;
}

// b'[j] = b_in[j] + sum_n c[n]*W_in[j,n]  (f32, exact)
__global__ __launch_bounds__(64) void bias_in(
        const float* __restrict__ W_in, const float* __restrict__ b_in,
        const float* __restrict__ cvec, float* __restrict__ bp) {
    int j = blockIdx.x;
    int lane = threadIdx.x;
    float s = 0.f;
    for (int n = lane; n < NIN; n += 64) s += cvec[n] * W_in[j * NIN + n];
    #pragma unroll
    for (int m = 1; m < 64; m <<= 1) s += __shfl_xor(s, m, 64);
    if (lane == 0) bp[j] = b_in[j] + s;
}

// ---------------------------------------------------------------------------
// Input GEMM (fp16x3 MFMA): pre[b,j] = X[b,:].Wp[j,:] + bp[j]
// grid (256, 2), block 256. Wave: 16 batch rows x 192 n-cols.
__global__ __launch_bounds__(256, 2) void gemm_in_mfma(
        const float* __restrict__ X, const _Float16* __restrict__ Wphi,
        const _Float16* __restrict__ Wplo, const float* __restrict__ bp,
        float* __restrict__ pre) {
    int tid = threadIdx.x;
    int w = tid >> 6, l = tid & 63, lr = l & 15, lq = l >> 4;
    int b0 = blockIdx.x * 64;
    int n0 = blockIdx.y * 192;
    const float* xrow = X + (size_t)(b0 + w * 16 + lr) * NIN;
    f32x4 acc[12], acr[12];
    #pragma unroll
    for (int ct = 0; ct < 12; ++ct)
        #pragma unroll
        for (int r = 0; r < 4; ++r) { acc[ct][r] = 0.f; acr[ct][r] = 0.f; }
    for (int kc = 0; kc < 24; ++kc) {
        int k0 = kc * 32 + lq * 8;
        float4 x0 = *(const float4*)(xrow + k0);
        float4 x1 = *(const float4*)(xrow + k0 + 4);
        float xv[8] = { x0.x, x0.y, x0.z, x0.w, x1.x, x1.y, x1.z, x1.w };
        f16x8 ahi, alo;
        #pragma unroll
        for (int j = 0; j < 8; ++j) {
            _Float16 h = (_Float16)xv[j];
            ahi[j] = h;
            alo[j] = (_Float16)((xv[j] - (float)h) * LOSCALE);
        }
        #pragma unroll
        for (int ct = 0; ct < 12; ++ct) {
            size_t off = (size_t)(n0 + ct * 16 + lr) * NIN + k0;
            f16x8 bhi = *(const f16x8*)(Wphi + off);
            f16x8 blo = *(const f16x8*)(Wplo + off);
            acc[ct] = __builtin_amdgcn_mfma_f32_16x16x32_f16(ahi, bhi, acc[ct], 0, 0, 0);
            acr[ct] = __builtin_amdgcn_mfma_f32_16x16x32_f16(ahi, blo, acr[ct], 0, 0, 0);
            acr[ct] = __builtin_amdgcn_mfma_f32_16x16x32_f16(alo, bhi, acr[ct], 0, 0, 0);
        }
    }
    {   // K tail 768..783 (16 valid): lanes lq>=2 contribute zeros
        f16x8 ahi, alo;
        #pragma unroll
        for (int j = 0; j < 8; ++j) { ahi[j] = (_Float16)0.f; alo[j] = (_Float16)0.f; }
        if (lq < 2) {
            float4 x0 = *(const float4*)(xrow + 768 + lq * 8);
            float4 x1 = *(const float4*)(xrow + 768 + lq * 8 + 4);
            float xv[8] = { x0.x, x0.y, x0.z, x0.w, x1.x, x1.y, x1.z, x1.w };
            #pragma unroll
            for (int j = 0; j < 8; ++j) {
                _Float16 h = (_Float16)xv[j];
                ahi[j] = h;
                alo[j] = (_Float16)((xv[j] - (float)h) * LOSCALE);
            }
        }
        #pragma unroll
        for (int ct = 0; ct < 12; ++ct) {
            f16x8 bhi, blo;
            #pragma unroll
            for (int j = 0; j < 8; ++j) { bhi[j] = (_Float16)0.f; blo[j] = (_Float16)0.f; }
            if (lq < 2) {
                size_t off = (size_t)(n0 + ct * 16 + lr) * NIN + 768 + lq * 8;
                bhi = *(const f16x8*)(Wphi + off);
                blo = *(const f16x8*)(Wplo + off);
            }
            acc[ct] = __builtin_amdgcn_mfma_f32_16x16x32_f16(ahi, bhi, acc[ct], 0, 0, 0);
            acr[ct] = __builtin_amdgcn_mfma_f32_16x16x32_f16(ahi, blo, acr[ct], 0, 0, 0);
            acr[ct] = __builtin_amdgcn_mfma_f32_16x16x32_f16(alo, bhi, acr[ct], 0, 0, 0);
        }
    }
    int brow = b0 + w * 16 + lq * 4;
    #pragma unroll
    for (int ct = 0; ct < 12; ++ct) {
        int n = n0 + ct * 16 + lr;
        float bias = bp[n];
        #pragma unroll
        for (int r = 0; r < 4; ++r)
            pre[(size_t)(brow + r) * NH + n] = acc[ct][r] + LOINV * acr[ct][r] + bias;
    }
}

// ---------------------------------------------------------------------------
// Normalize + hi/lo split: y = a[j]*relu(pre)+c[j]; 8 elems/thread
__global__ __launch_bounds__(256) void norm_hl(
        const float* __restrict__ pre, const float* __restrict__ a,
        const float* __restrict__ c, _Float16* __restrict__ hi,
        _Float16* __restrict__ lo) {
    int idx = blockIdx.x * 256 + threadIdx.x;   // over B*NH/8
    int j = (idx * 8) % NH;
    float4 v0 = ((const float4*)pre)[idx * 2];
    float4 v1 = ((const float4*)pre)[idx * 2 + 1];
    float y[8] = {
        a[j+0] * fmaxf(v0.x, 0.f) + c[j+0], a[j+1] * fmaxf(v0.y, 0.f) + c[j+1],
        a[j+2] * fmaxf(v0.z, 0.f) + c[j+2], a[j+3] * fmaxf(v0.w, 0.f) + c[j+3],
        a[j+4] * fmaxf(v1.x, 0.f) + c[j+4], a[j+5] * fmaxf(v1.y, 0.f) + c[j+5],
        a[j+6] * fmaxf(v1.z, 0.f) + c[j+6], a[j+7] * fmaxf(v1.w, 0.f) + c[j+7] };
    f16x8 h8, l8;
    #pragma unroll
    for (int jj = 0; jj < 8; ++jj) {
        _Float16 h = (_Float16)y[jj];
        h8[jj] = h;
        l8[jj] = (_Float16)((y[jj] - (float)h) * LOSCALE);
    }
    *(f16x8*)(hi + (size_t)idx * 8) = h8;
    *(f16x8*)(lo + (size_t)idx * 8) = l8;
}

// ---------------------------------------------------------------------------
// Gates from reconstructed acts (hi + lo/2048): fp32 dot + clip.
__global__ __launch_bounds__(256) void gate_kernel(
        const _Float16* __restrict__ aHi, const _Float16* __restrict__ aLo,
        const float* __restrict__ Wg_l, float* __restrict__ gateT,
        float* __restrict__ tg, int firstLayer) {
    int lane = threadIdx.x & 63;
    int w = threadIdx.x >> 6;
    int b = blockIdx.x * 4 + w;
    float a[6];
    #pragma unroll
    for (int s = 0; s < 6; ++s) {
        size_t off = (size_t)b * NH + s * 64 + lane;
        a[s] = (float)aHi[off] + LOINV * (float)aLo[off];
    }
    float gsum = 0.f, gval = 0.f;
    #pragma unroll
    for (int s = 0; s < 6; ++s) {
        #pragma unroll
        for (int t = 0; t < 6; ++t) {
            float p = a[s] * Wg_l[(s * 6 + t) * 64 + lane];
            #pragma unroll
            for (int m = 1; m < 64; m <<= 1) p += __shfl_xor(p, m, 64);
            float gcl = fminf(fmaxf(p, 0.f), 1.f);
            gsum += gcl;
            if (lane == s * 6 + t) gval = gcl;
        }
    }
    if (lane < 36) gateT[(size_t)lane * BATCH + b] = gval;
    if (lane == 0) tg[b] = (firstLayer ? 0.f : tg[b]) + gsum;
}

// ---------------------------------------------------------------------------
// Routed layer (fp16x3 MFMA, transposed D^T[e][b]); s-outer so acts frags
// load once per source; acc[t][ct] static-indexed.
// grid (B/32), block 256 (4 waves). Wave w: e in [w*16, w*16+16), 32 batch.
__global__ __launch_bounds__(256, 2) void layer_data_mfma(
        const _Float16* __restrict__ aHi, const _Float16* __restrict__ aLo,
        const float* __restrict__ gateT, const _Float16* __restrict__ Wdhi,
        const _Float16* __restrict__ Wdlo, const float* __restrict__ bd_l,
        float* __restrict__ pre) {
    int tid = threadIdx.x;
    int w = tid >> 6, l = tid & 63, lr = l & 15, lq = l >> 4;
    int b0 = blockIdx.x * 32;
    int e0 = w * 16;
    f32x4 acc[6][2];
    #pragma unroll
    for (int t = 0; t < 6; ++t)
        #pragma unroll
        for (int ct = 0; ct < 2; ++ct)
            #pragma unroll
            for (int r = 0; r < 4; ++r) acc[t][ct][r] = 0.f;
    for (int s = 0; s < 6; ++s) {
        f16x8 bhi[2][2], blo[2][2];   // [ct][ks]
        #pragma unroll
        for (int ct = 0; ct < 2; ++ct) {
            size_t arow = (size_t)(b0 + ct * 16 + lr) * NH + s * 64 + lq * 8;
            #pragma unroll
            for (int ks = 0; ks < 2; ++ks) {
                bhi[ct][ks] = *(const f16x8*)(aHi + arow + ks * 32);
                blo[ct][ks] = *(const f16x8*)(aLo + arow + ks * 32);
            }
        }
        #pragma unroll
        for (int t = 0; t < 6; ++t) {
            float g0 = gateT[(size_t)(s * 6 + t) * BATCH + b0 + lr];
            float g1 = gateT[(size_t)(s * 6 + t) * BATCH + b0 + 16 + lr];
            size_t wb = ((size_t)(s * 6 + t) * 64 + e0 + lr) * 64 + lq * 8;
            f16x8 ah0 = *(const f16x8*)(Wdhi + wb);
            f16x8 ah1 = *(const f16x8*)(Wdhi + wb + 32);
            f16x8 al0 = *(const f16x8*)(Wdlo + wb);
            f16x8 al1 = *(const f16x8*)(Wdlo + wb + 32);
            float bdv[4];
            #pragma unroll
            for (int r = 0; r < 4; ++r)
                bdv[r] = bd_l[(s * 6 + t) * 64 + e0 + lq * 4 + r];
            #pragma unroll
            for (int ct = 0; ct < 2; ++ct) {
                f32x4 ph, pc;
                #pragma unroll
                for (int r = 0; r < 4; ++r) { ph[r] = 0.f; pc[r] = 0.f; }
                ph = __builtin_amdgcn_mfma_f32_16x16x32_f16(ah0, bhi[ct][0], ph, 0, 0, 0);
                ph = __builtin_amdgcn_mfma_f32_16x16x32_f16(ah1, bhi[ct][1], ph, 0, 0, 0);
                pc = __builtin_amdgcn_mfma_f32_16x16x32_f16(ah0, blo[ct][0], pc, 0, 0, 0);
                pc = __builtin_amdgcn_mfma_f32_16x16x32_f16(ah1, blo[ct][1], pc, 0, 0, 0);
                pc = __builtin_amdgcn_mfma_f32_16x16x32_f16(al0, bhi[ct][0], pc, 0, 0, 0);
                pc = __builtin_amdgcn_mfma_f32_16x16x32_f16(al1, bhi[ct][1], pc, 0, 0, 0);
                float g = ct ? g1 : g0;
                #pragma unroll
                for (int r = 0; r < 4; ++r)
                    acc[t][ct][r] += g * (ph[r] + LOINV * pc[r] + bdv[r]);
            }
        }
    }
    #pragma unroll
    for (int t = 0; t < 6; ++t)
        #pragma unroll
        for (int ct = 0; ct < 2; ++ct)
            #pragma unroll
            for (int r = 0; r < 4; ++r)
                pre[(size_t)(b0 + ct * 16 + lr) * NH + t * 64 + e0 + lq * 4 + r]
                    = acc[t][ct][r];
}

// ---------------------------------------------------------------------------
// Output head + total_gate copy (fp32 exact from reconstructed acts)
__global__ __launch_bounds__(256) void out_kernel(
        const _Float16* __restrict__ aHi, const _Float16* __restrict__ aLo,
        const float* __restrict__ W_out, const float* __restrict__ tg,
        float* __restrict__ dout) {
    int lane = threadIdx.x & 63;
    int w = threadIdx.x >> 6;
    int b = blockIdx.x * 4 + w;
    float a[6];
    #pragma unroll
    for (int s = 0; s < 6; ++s) {
        size_t off = (size_t)b * NH + s * 64 + lane;
        a[s] = (float)aHi[off] + LOINV * (float)aLo[off];
    }
    float ov = 0.f;
    #pragma unroll
    for (int o = 0; o < NOUT; ++o) {
        float p = 0.f;
        #pragma unroll
        for (int s = 0; s < 6; ++s) p += a[s] * W_out[(s * NOUT + o) * 64 + lane];
        #pragma unroll
        for (int m = 1; m < 64; m <<= 1) p += __shfl_xor(p, m, 64);
        if (lane == o) ov = p;
    }
    if (lane < NOUT) dout[(size_t)b * NOUT + lane] = ov;
    if (lane == 0) dout[(size_t)BATCH * NOUT + b] = tg[b];
}

// ---------------------------------------------------------------------------
extern "C" void kernel_launch(void* const* d_in, const int* in_sizes, int n_in,
                              void* d_out, int out_size, void* d_ws, size_t ws_size,
                              hipStream_t stream) {
    const float* x        = (const float*)d_in[0];
    const float* gamma_in = (const float*)d_in[1];
    const float* beta_in  = (const float*)d_in[2];
    const float* W_in     = (const float*)d_in[3];
    const float* b_in     = (const float*)d_in[4];
    const float* Wg       = (const float*)d_in[5];
    const float* Wd       = (const float*)d_in[6];
    const float* bd       = (const float*)d_in[7];
    const float* gamma_h  = (const float*)d_in[8];
    const float* beta_h   = (const float*)d_in[9];
    const float* W_out    = (const float*)d_in[10];
    float* dout = (float*)d_out;
    float* ws = (float*)d_ws;

    // workspace layout (float offsets), total 13,558,784 floats = 51.7 MiB
    float* psum  = ws;                          //     0 .. 32768
    float* psq   = ws + 32768;                  // 32768 .. 65536
    float* avec  = ws + 65536;                  // 1024
    float* cvec  = ws + 66560;                  // 1024
    float* bp    = ws + 67584;                  // 1024
    float* pre   = ws + 68608;                  // B*NH f32
    _Float16* actsHi = (_Float16*)(ws + 6360064);   // B*NH f16
    _Float16* actsLo = (_Float16*)(ws + 9505792);   // B*NH f16
    float* gateT = ws + 12651520;               // 36*B f32
    float* tg    = ws + 13241344;               // B
    _Float16* WpHi = (_Float16*)(ws + 13257728);    // 384*784 f16
    _Float16* WpLo = (_Float16*)(ws + 13408256);    // 384*784 f16
    // per-layer Wd hi/lo buffers ALIAS the Wp region (Wp dead after gemm_in)
    _Float16* WdHiCur = WpHi;                   // 36*4096 f16 (fits)
    _Float16* WdLoCur = WpLo;

    dim3 blk(256);

    // ---- prep: input BN fold + weight split-cast
    stats_partial<<<dim3(4, NPART), blk, 0, stream>>>(x, NIN, 0, psum, psq);
    stats_finalize<<<dim3(4), blk, 0, stream>>>(psum, psq, NIN, gamma_in, beta_in, avec, cvec);
    scale_win_hl<<<dim3((NH * NIN / 4 + 255) / 256), blk, 0, stream>>>(W_in, avec, WpHi, WpLo);
    bias_in<<<dim3(NH), dim3(64), 0, stream>>>(W_in, b_in, cvec, bp);

    // ---- input GEMM (fp16x3 MFMA) -> pre f32
    gemm_in_mfma<<<dim3(BATCH / 64, 2), blk, 0, stream>>>(x, WpHi, WpLo, bp, pre);

    // ---- hidden layers
    for (int j = 0; j < NLAYERS; ++j) {
        stats_partial<<<dim3(2, NPART), blk, 0, stream>>>(pre, NH, 1, psum, psq);
        stats_finalize<<<dim3(2), blk, 0, stream>>>(psum, psq, NH,
                gamma_h + j * NH, beta_h + j * NH, avec, cvec);
        norm_hl<<<dim3(BATCH * NH / 8 / 256), blk, 0, stream>>>(pre, avec, cvec, actsHi, actsLo);
        if (j < NLAYERS - 1) {
            int l = j;
            conv_hl<<<dim3(144), blk, 0, stream>>>(
                    Wd + (size_t)l * 36 * 4096, WdHiCur, WdLoCur, 36 * 4096 / 4);
            gate_kernel<<<dim3(BATCH / 4), blk, 0, stream>>>(
                    actsHi, actsLo, Wg + (size_t)l * 36 * 64, gateT, tg, l == 0);
            layer_data_mfma<<<dim3(BATCH / 32), blk, 0, stream>>>(
                    actsHi, actsLo, gateT, WdHiCur, WdLoCur,
                    bd + (size_t)l * 36 * 64, pre);
        }
    }

    // ---- output head + total_gate
    out_kernel<<<dim3(BATCH / 4), blk, 0, stream>>>(actsHi, actsLo, W_out, tg, dout);
}